// Round 5
// baseline (2773.460 us; speedup 1.0000x reference)
//
#include <hip/hip_runtime.h>
#include <hip/hip_bf16.h>
#include <math.h>

// ---- problem constants ----
#define BATCH   8
#define C_IN    3
#define IMG_SZ  224
#define P_SZ    16
#define NPATCH  196                 // (224/16)^2
#define MSEQ    197                 // NPATCH + cls
#define DDIM    192
#define EDIM    384
#define NSTATE  16
#define ENDIM   (EDIM*NSTATE)       // 6144
#define LLAYERS 2
#define ROWS    (BATCH*MSEQ)        // 1576
#define PROWS   (BATCH*NPATCH)      // 1568
#define PATCH_K (C_IN*P_SZ*P_SZ)    // 768

// precise silu (enters the scan only linearly)
__device__ __forceinline__ float silu_f(float x) { return x / (1.f + expf(-x)); }

// ------------------------------------------------------------------
// patchify: img (B,3,224,224) -> patches (PROWS, 768)
// ------------------------------------------------------------------
__global__ __launch_bounds__(256) void patchify_k(const float* __restrict__ img,
                                                  float* __restrict__ out) {
    int idx = blockIdx.x * 256 + threadIdx.x;
    if (idx >= PROWS * PATCH_K) return;
    int r = idx / PATCH_K, col = idx - r * PATCH_K;
    int b = r / NPATCH, p = r - b * NPATCH;
    int ph = p / 14, pw = p - ph * 14;
    int c = col >> 8, rem = col & 255, py = rem >> 4, px = rem & 15;
    out[idx] = img[((b * C_IN + c) * IMG_SZ + ph * P_SZ + py) * IMG_SZ + pw * P_SZ + px];
}

// ------------------------------------------------------------------
// assemble x = concat(cls, xemb) + pos   -> (B, MSEQ, DDIM)
// ------------------------------------------------------------------
__global__ __launch_bounds__(256) void assemble_k(const float* __restrict__ xemb,
                                                  const float* __restrict__ cls,
                                                  const float* __restrict__ pos,
                                                  float* __restrict__ x) {
    int idx = blockIdx.x * 256 + threadIdx.x;
    if (idx >= ROWS * DDIM) return;
    int d = idx % DDIM;
    int bm = idx / DDIM;
    int m = bm % MSEQ, b = bm / MSEQ;
    float v;
    if (m == 0) v = cls[d];
    else        v = xemb[((b * NPATCH) + (m - 1)) * DDIM + d];
    x[idx] = v + pos[m * DDIM + d];
}

// ------------------------------------------------------------------
// layernorm over last dim (DDIM=192), one wave per row
// ------------------------------------------------------------------
__global__ __launch_bounds__(256) void layernorm_k(const float* __restrict__ x,
                                                   const float* __restrict__ g,
                                                   const float* __restrict__ b,
                                                   float* __restrict__ o, int nrows) {
    int wave = threadIdx.x >> 6;
    int lane = threadIdx.x & 63;
    int row = blockIdx.x * 4 + wave;
    if (row >= nrows) return;
    const float* xr = x + (long)row * DDIM;
    float v0 = xr[lane], v1 = xr[lane + 64], v2 = xr[lane + 128];
    float s = v0 + v1 + v2;
    #pragma unroll
    for (int off = 1; off < 64; off <<= 1) s += __shfl_xor(s, off);
    float mu = s * (1.f / 192.f);
    float d0 = v0 - mu, d1 = v1 - mu, d2 = v2 - mu;
    float q = d0 * d0 + d1 * d1 + d2 * d2;
    #pragma unroll
    for (int off = 1; off < 64; off <<= 1) q += __shfl_xor(q, off);
    float inv = rsqrtf(q * (1.f / 192.f) + 1e-5f);
    float* orow = o + (long)row * DDIM;
    orow[lane]       = d0 * inv * g[lane]       + b[lane];
    orow[lane + 64]  = d1 * inv * g[lane + 64]  + b[lane + 64];
    orow[lane + 128] = d2 * inv * g[lane + 128] + b[lane + 128];
}

// ------------------------------------------------------------------
// fp32 GEMM, tile 128 x (64*HALVES), 8 x (4*HALVES) per thread.
// C[M,N] = A[M,K] @ W[K,N] + bias1 (+bias2) (+resid); SP = CR softplus
// (computed in fp64, rounded to fp32 — feeds the chaotic scan).
// Ws is stored as HALVES separate 64-col panels so LDS reads stay
// <=2-way bank-conflicted (16 addrs * 16B = 256B span per panel).
// requires N % (64*HALVES) == 0, K % 16 == 0.
// ------------------------------------------------------------------
#define BM 128
#define BK 16
template<int HALVES, bool SP>
__global__ __launch_bounds__(256) void gemm_t(const float* __restrict__ A,
                                              const float* __restrict__ W,
                                              const float* __restrict__ bias1,
                                              const float* __restrict__ bias2,
                                              const float* __restrict__ resid,
                                              float* __restrict__ C,
                                              int M, int N, int K) {
    __shared__ float As[BK][BM + 4];
    __shared__ float Ws[HALVES][BK][64];
    int t = threadIdx.x;
    int tx = t & 15, ty = t >> 4;
    long colBase = (long)blockIdx.x * (HALVES * 64);
    int rowBase = blockIdx.y * BM;
    float acc[8][HALVES * 4] = {};
    int a_m = t >> 1, a_k = (t & 1) << 3;      // A: 2 float4 per thread
    int w_k = t >> 4, w_n = (t & 15) << 2;     // W: 1 float4 per panel per thread
    for (int k0 = 0; k0 < K; k0 += BK) {
        int ar = rowBase + a_m;
        float4 av0 = make_float4(0.f, 0.f, 0.f, 0.f), av1 = av0;
        if (ar < M) {
            const float* ap = &A[(long)ar * K + k0 + a_k];
            av0 = *(const float4*)ap;
            av1 = *(const float4*)(ap + 4);
        }
        As[a_k + 0][a_m] = av0.x; As[a_k + 1][a_m] = av0.y;
        As[a_k + 2][a_m] = av0.z; As[a_k + 3][a_m] = av0.w;
        As[a_k + 4][a_m] = av1.x; As[a_k + 5][a_m] = av1.y;
        As[a_k + 6][a_m] = av1.z; As[a_k + 7][a_m] = av1.w;
        #pragma unroll
        for (int hh = 0; hh < HALVES; ++hh)
            *(float4*)&Ws[hh][w_k][w_n] =
                *(const float4*)&W[(long)(k0 + w_k) * N + colBase + hh * 64 + w_n];
        __syncthreads();
        #pragma unroll
        for (int kk = 0; kk < BK; ++kk) {
            float4 a0 = *(const float4*)&As[kk][ty << 3];
            float4 a1 = *(const float4*)&As[kk][(ty << 3) + 4];
            float ar8[8] = {a0.x, a0.y, a0.z, a0.w, a1.x, a1.y, a1.z, a1.w};
            #pragma unroll
            for (int hh = 0; hh < HALVES; ++hh) {
                float4 w = *(const float4*)&Ws[hh][kk][tx << 2];
                float wr[4] = {w.x, w.y, w.z, w.w};
                #pragma unroll
                for (int i = 0; i < 8; ++i)
                    #pragma unroll
                    for (int j = 0; j < 4; ++j)
                        acc[i][hh * 4 + j] += ar8[i] * wr[j];
            }
        }
        __syncthreads();
    }
    #pragma unroll
    for (int i = 0; i < 8; ++i) {
        int r = rowBase + (ty << 3) + i;
        if (r >= M) break;
        #pragma unroll
        for (int hh = 0; hh < HALVES; ++hh) {
            long cb = colBase + hh * 64 + (tx << 2);
            float vv[4];
            #pragma unroll
            for (int j = 0; j < 4; ++j) {
                long c = cb + j;
                float v = acc[i][hh * 4 + j] + bias1[c];
                if (bias2) v += bias2[c];
                if (SP) {  // correctly-rounded fp32 softplus via fp64
                    double vd = (double)v;
                    v = (float)(log1p(exp(-fabs(vd))) + fmax(vd, 0.0));
                }
                if (resid) v += resid[(long)r * N + c];
                vv[j] = v;
            }
            float4 o; o.x = vv[0]; o.y = vv[1]; o.z = vv[2]; o.w = vv[3];
            *(float4*)&C[(long)r * N + cb] = o;
        }
    }
}

// ------------------------------------------------------------------
// fused depthwise conv (fwd + bwd) + SiLU
// ------------------------------------------------------------------
__global__ __launch_bounds__(256) void dwconv_k(const float* __restrict__ xp,
                                                const float* __restrict__ wf,
                                                const float* __restrict__ bf,
                                                const float* __restrict__ wb,
                                                const float* __restrict__ bb,
                                                float* __restrict__ xf,
                                                float* __restrict__ xb) {
    int idx = blockIdx.x * 256 + threadIdx.x;
    if (idx >= ROWS * EDIM) return;
    int e = idx % EDIM;
    int bm = idx / EDIM;
    int m = bm % MSEQ, b = bm / MSEQ;
    const float* base = xp + (long)b * MSEQ * EDIM + e;
    float xm1 = (m > 0)        ? base[(m - 1) * EDIM] : 0.f;
    float x0  =                  base[m * EDIM];
    float xp1 = (m < MSEQ - 1) ? base[(m + 1) * EDIM] : 0.f;
    float f = wf[e * 3 + 0] * xm1 + wf[e * 3 + 1] * x0 + wf[e * 3 + 2] * xp1 + bf[e];
    float r = wb[e * 3 + 0] * xp1 + wb[e * 3 + 1] * x0 + wb[e * 3 + 2] * xm1 + bb[e];
    xf[idx] = silu_f(f);
    xb[idx] = silu_f(r);
}

// ------------------------------------------------------------------
// SSM recurrence — fp32 storage semantics, CR transcendentals
// (fp64-computed, rounded to fp32). Delta is PRE-COMPUTED (CR softplus
// in the D-GEMM epilogue) — bit-identical to computing it here, but
// 16x less transcendental work. fp contract OFF so the S/h chain
// rounds exactly like numpy. 64-thread blocks spread 768 blocks
// across all 256 CUs (was 192 blocks / 192 CUs).
// n-sum uses numpy's pairwise-16 order: xor8 first, then 1,2,4.
// ------------------------------------------------------------------
__global__ __launch_bounds__(64) void ssm_scan_k(const float* __restrict__ Bm,
                                                 const float* __restrict__ Cm,
                                                 const float* __restrict__ Dlt,
                                                 const float* __restrict__ xs,
                                                 const float* __restrict__ Apar,
                                                 float* __restrict__ y) {
#pragma clang fp contract(off)
    int tid = blockIdx.x * 64 + threadIdx.x;     // B*E*N total = 49152
    int n = tid & (NSTATE - 1);
    int e = (tid / NSTATE) % EDIM;
    int b = tid / (EDIM * NSTATE);
    float Ap = Apar[e * NSTATE + n];
    float cumlog = 0.f, cumsign = 1.f, S = 0.f;
    int bcIdx = b * MSEQ * ENDIM + e * NSTATE + n;   // advances by ENDIM per m
    int dxIdx = b * MSEQ * EDIM + e;                 // advances by EDIM per m
    bool leader = ((threadIdx.x & 15) == 0);
    for (int m = 0; m < MSEQ; ++m) {
        float delta = Dlt[dxIdx];                     // CR softplus, precomputed
        float xv = xs[dxIdx];
        float Bv = Bm[bcIdx];
        float Cv = Cm[bcIdx];
        float A = delta * Ap;                         // exact fp32 product
        float sa = (A > 0.f) ? 1.f : ((A < 0.f) ? -1.f : 0.f);
        cumsign = cumsign * sa;
        float absA = fmaxf(fabsf(A), 1e-6f);
        float lg = (float)log((double)absA);          // CR fp32 log
        cumlog = cumlog + lg;                         // fp32 cumsum
        float ex = (float)exp((double)cumlog);        // CR fp32 exp
        float P = cumsign * ex;
        float tt = P + 1e-6f;                         // exact near-cancel
        float invP = 1.0f / tt;                       // IEEE fp32 div
        float Bfull = delta * Bv;
        float t1 = invP * Bfull;
        float t2 = t1 * xv;
        S = S + t2;
        float h = P * S;
        float contrib = h * Cv;
        // numpy pairwise-16 reduction order
        contrib += __shfl_xor(contrib, 8);
        contrib += __shfl_xor(contrib, 1);
        contrib += __shfl_xor(contrib, 2);
        contrib += __shfl_xor(contrib, 4);
        if (leader) y[dxIdx] = contrib;
        bcIdx += ENDIM;
        dxIdx += EDIM;
    }
}

// ------------------------------------------------------------------
// combine: yc = (yf + yb) * silu(z)
// ------------------------------------------------------------------
__global__ __launch_bounds__(256) void combine_k(const float* __restrict__ yf,
                                                 const float* __restrict__ yb,
                                                 const float* __restrict__ z,
                                                 float* __restrict__ yc) {
    int idx = blockIdx.x * 256 + threadIdx.x;
    if (idx >= ROWS * EDIM) return;
    yc[idx] = (yf[idx] + yb[idx]) * silu_f(z[idx]);
}

// ------------------------------------------------------------------
template<int HALVES, bool SP>
static inline void gemmL(hipStream_t s, const float* A, const float* W, const float* b1,
                         const float* b2, const float* resid, float* C,
                         int M, int N, int K) {
    dim3 g(N / (HALVES * 64), (M + BM - 1) / BM);
    gemm_t<HALVES, SP><<<g, 256, 0, s>>>(A, W, b1, b2, resid, C, M, N, K);
}

extern "C" void kernel_launch(void* const* d_in, const int* in_sizes, int n_in,
                              void* d_out, int out_size, void* d_ws, size_t ws_size,
                              hipStream_t stream) {
    const float* img     = (const float*)d_in[0];
    const float* patch_w = (const float*)d_in[1];
    const float* patch_b = (const float*)d_in[2];
    const float* cls     = (const float*)d_in[3];
    const float* pos     = (const float*)d_in[4];
    const float* ln_g    = (const float*)d_in[5];
    const float* ln_b    = (const float*)d_in[6];
    const float* Wx  = (const float*)d_in[7];  const float* bx  = (const float*)d_in[8];
    const float* Wz  = (const float*)d_in[9];  const float* bz  = (const float*)d_in[10];
    const float* cwf = (const float*)d_in[11]; const float* cbf = (const float*)d_in[12];
    const float* cwb = (const float*)d_in[13]; const float* cbb = (const float*)d_in[14];
    const float* WBf = (const float*)d_in[15]; const float* bBf = (const float*)d_in[16];
    const float* WCf = (const float*)d_in[17]; const float* bCf = (const float*)d_in[18];
    const float* WDf = (const float*)d_in[19]; const float* bDf = (const float*)d_in[20];
    const float* Af  = (const float*)d_in[21]; const float* dbf = (const float*)d_in[22];
    const float* WBb = (const float*)d_in[23]; const float* bBb = (const float*)d_in[24];
    const float* WCb = (const float*)d_in[25]; const float* bCb = (const float*)d_in[26];
    const float* WDb = (const float*)d_in[27]; const float* bDb = (const float*)d_in[28];
    const float* Ab  = (const float*)d_in[29]; const float* dbb = (const float*)d_in[30];
    const float* Wout= (const float*)d_in[31]; const float* bout= (const float*)d_in[32];
    const float* ng  = (const float*)d_in[33]; const float* nb  = (const float*)d_in[34];

    float* ws = (float*)d_ws;
    float* xA  = ws;
    float* xB  = xA + (size_t)ROWS * DDIM;
    float* xn  = xB + (size_t)ROWS * DDIM;
    float* xp  = xn + (size_t)ROWS * DDIM;
    float* zb  = xp + (size_t)ROWS * EDIM;
    float* xfb = zb + (size_t)ROWS * EDIM;
    float* xbb = xfb + (size_t)ROWS * EDIM;
    float* yfb = xbb + (size_t)ROWS * EDIM;
    float* ybb = yfb + (size_t)ROWS * EDIM;
    float* ycb = ybb + (size_t)ROWS * EDIM;
    float* dlt = ycb + (size_t)ROWS * EDIM;
    float* Bmb = dlt + (size_t)ROWS * EDIM;          // ROWS*ENDIM
    float* Cmb = Bmb + (size_t)ROWS * ENDIM;
    // patchify scratch aliases the (not-yet-needed) Bm buffer
    float* patches = Bmb;                             // PROWS*PATCH_K
    float* xemb    = Bmb + (size_t)PROWS * PATCH_K;   // PROWS*DDIM

    // --- patch embedding ---
    patchify_k<<<(PROWS * PATCH_K + 255) / 256, 256, 0, stream>>>(img, patches);
    gemmL<1,false>(stream, patches, patch_w, patch_b, nullptr, nullptr, xemb, PROWS, DDIM, PATCH_K);
    assemble_k<<<(ROWS * DDIM + 255) / 256, 256, 0, stream>>>(xemb, cls, pos, xA);

    float* cur = xA; float* nxt = xB;
    for (int i = 0; i < LLAYERS; ++i) {
        layernorm_k<<<(ROWS + 3) / 4, 256, 0, stream>>>(cur, ln_g + i * DDIM, ln_b + i * DDIM, xn, ROWS);
        gemmL<2,false>(stream, xn, Wx + (size_t)i * DDIM * EDIM, bx + i * EDIM, nullptr, nullptr, xp, ROWS, EDIM, DDIM);
        gemmL<2,false>(stream, xn, Wz + (size_t)i * DDIM * EDIM, bz + i * EDIM, nullptr, nullptr, zb, ROWS, EDIM, DDIM);
        dwconv_k<<<(ROWS * EDIM + 255) / 256, 256, 0, stream>>>(xp, cwf + i * EDIM * 3, cbf + i * EDIM,
                                                                cwb + i * EDIM * 3, cbb + i * EDIM, xfb, xbb);
        // forward branch (dlt holds CR-softplus'd Delta from the GEMM epilogue)
        gemmL<2,false>(stream, xfb, WBf + (size_t)i * EDIM * ENDIM, bBf + i * ENDIM, nullptr, nullptr, Bmb, ROWS, ENDIM, EDIM);
        gemmL<2,false>(stream, xfb, WCf + (size_t)i * EDIM * ENDIM, bCf + i * ENDIM, nullptr, nullptr, Cmb, ROWS, ENDIM, EDIM);
        gemmL<2,true >(stream, xfb, WDf + (size_t)i * EDIM * EDIM, bDf + i * EDIM, dbf + i * EDIM, nullptr, dlt, ROWS, EDIM, EDIM);
        ssm_scan_k<<<(BATCH * EDIM * NSTATE) / 64, 64, 0, stream>>>(Bmb, Cmb, dlt, xfb, Af + i * EDIM * NSTATE, yfb);
        // backward branch
        gemmL<2,false>(stream, xbb, WBb + (size_t)i * EDIM * ENDIM, bBb + i * ENDIM, nullptr, nullptr, Bmb, ROWS, ENDIM, EDIM);
        gemmL<2,false>(stream, xbb, WCb + (size_t)i * EDIM * ENDIM, bCb + i * ENDIM, nullptr, nullptr, Cmb, ROWS, ENDIM, EDIM);
        gemmL<2,true >(stream, xbb, WDb + (size_t)i * EDIM * EDIM, bDb + i * EDIM, dbb + i * EDIM, nullptr, dlt, ROWS, EDIM, EDIM);
        ssm_scan_k<<<(BATCH * EDIM * NSTATE) / 64, 64, 0, stream>>>(Bmb, Cmb, dlt, xbb, Ab + i * EDIM * NSTATE, ybb);

        combine_k<<<(ROWS * EDIM + 255) / 256, 256, 0, stream>>>(yfb, ybb, zb, ycb);
        gemmL<1,false>(stream, ycb, Wout + (size_t)i * EDIM * DDIM, bout + i * DDIM, nullptr, cur, nxt, ROWS, DDIM, EDIM);
        float* t = cur; cur = nxt; nxt = t;
    }
    layernorm_k<<<(ROWS + 3) / 4, 256, 0, stream>>>(cur, ng, nb, (float*)d_out, ROWS);
}

// Round 6
// 1424.721 us; speedup vs baseline: 1.9467x; 1.9467x over previous
//
#include <hip/hip_runtime.h>
#include <hip/hip_bf16.h>
#include <math.h>

// ---- problem constants ----
#define BATCH   8
#define C_IN    3
#define IMG_SZ  224
#define P_SZ    16
#define NPATCH  196                 // (224/16)^2
#define MSEQ    197                 // NPATCH + cls
#define DDIM    192
#define EDIM    384
#define NSTATE  16
#define ENDIM   (EDIM*NSTATE)       // 6144
#define LLAYERS 2
#define ROWS    (BATCH*MSEQ)        // 1576
#define PROWS   (BATCH*NPATCH)      // 1568
#define PATCH_K (C_IN*P_SZ*P_SZ)    // 768

// precise silu (enters the scan only linearly)
__device__ __forceinline__ float silu_f(float x) { return x / (1.f + expf(-x)); }

// ------------------------------------------------------------------
// patchify: img (B,3,224,224) -> patches (PROWS, 768)
// ------------------------------------------------------------------
__global__ __launch_bounds__(256) void patchify_k(const float* __restrict__ img,
                                                  float* __restrict__ out) {
    int idx = blockIdx.x * 256 + threadIdx.x;
    if (idx >= PROWS * PATCH_K) return;
    int r = idx / PATCH_K, col = idx - r * PATCH_K;
    int b = r / NPATCH, p = r - b * NPATCH;
    int ph = p / 14, pw = p - ph * 14;
    int c = col >> 8, rem = col & 255, py = rem >> 4, px = rem & 15;
    out[idx] = img[((b * C_IN + c) * IMG_SZ + ph * P_SZ + py) * IMG_SZ + pw * P_SZ + px];
}

// ------------------------------------------------------------------
// assemble x = concat(cls, xemb) + pos   -> (B, MSEQ, DDIM)
// ------------------------------------------------------------------
__global__ __launch_bounds__(256) void assemble_k(const float* __restrict__ xemb,
                                                  const float* __restrict__ cls,
                                                  const float* __restrict__ pos,
                                                  float* __restrict__ x) {
    int idx = blockIdx.x * 256 + threadIdx.x;
    if (idx >= ROWS * DDIM) return;
    int d = idx % DDIM;
    int bm = idx / DDIM;
    int m = bm % MSEQ, b = bm / MSEQ;
    float v;
    if (m == 0) v = cls[d];
    else        v = xemb[((b * NPATCH) + (m - 1)) * DDIM + d];
    x[idx] = v + pos[m * DDIM + d];
}

// ------------------------------------------------------------------
// layernorm over last dim (DDIM=192), one wave per row
// ------------------------------------------------------------------
__global__ __launch_bounds__(256) void layernorm_k(const float* __restrict__ x,
                                                   const float* __restrict__ g,
                                                   const float* __restrict__ b,
                                                   float* __restrict__ o, int nrows) {
    int wave = threadIdx.x >> 6;
    int lane = threadIdx.x & 63;
    int row = blockIdx.x * 4 + wave;
    if (row >= nrows) return;
    const float* xr = x + (long)row * DDIM;
    float v0 = xr[lane], v1 = xr[lane + 64], v2 = xr[lane + 128];
    float s = v0 + v1 + v2;
    #pragma unroll
    for (int off = 1; off < 64; off <<= 1) s += __shfl_xor(s, off);
    float mu = s * (1.f / 192.f);
    float d0 = v0 - mu, d1 = v1 - mu, d2 = v2 - mu;
    float q = d0 * d0 + d1 * d1 + d2 * d2;
    #pragma unroll
    for (int off = 1; off < 64; off <<= 1) q += __shfl_xor(q, off);
    float inv = rsqrtf(q * (1.f / 192.f) + 1e-5f);
    float* orow = o + (long)row * DDIM;
    orow[lane]       = d0 * inv * g[lane]       + b[lane];
    orow[lane + 64]  = d1 * inv * g[lane + 64]  + b[lane + 64];
    orow[lane + 128] = d2 * inv * g[lane + 128] + b[lane + 128];
}

// ------------------------------------------------------------------
// BIG fp32 GEMM for the B/C projections (N=6144), tile 128x128,
// 8x8 per thread, 256 threads. gridDim.z=2 selects {W0->C0, W1->C1}
// with the SAME A (halves effective A traffic, doubles parallelism).
// ------------------------------------------------------------------
#define BM 128
#define BK 16
__global__ __launch_bounds__(256) void gemm_big(const float* __restrict__ A,
                                                const float* __restrict__ W0,
                                                const float* __restrict__ b0,
                                                float* __restrict__ C0,
                                                const float* __restrict__ W1,
                                                const float* __restrict__ b1,
                                                float* __restrict__ C1,
                                                int M, int N, int K) {
    const float* W    = blockIdx.z ? W1 : W0;
    const float* bias = blockIdx.z ? b1 : b0;
    float*       C    = blockIdx.z ? C1 : C0;
    __shared__ float As[BK][BM + 4];
    __shared__ float Ws[2][BK][64];
    int t = threadIdx.x;
    int tx = t & 15, ty = t >> 4;
    long colBase = (long)blockIdx.x * 128;
    int rowBase = blockIdx.y * BM;
    float acc[8][8] = {};
    int a_m = t >> 1, a_k = (t & 1) << 3;      // A: 2 float4 per thread
    int w_k = t >> 4, w_n = (t & 15) << 2;     // W: 1 float4 per panel per thread
    for (int k0 = 0; k0 < K; k0 += BK) {
        int ar = rowBase + a_m;
        float4 av0 = make_float4(0.f, 0.f, 0.f, 0.f), av1 = av0;
        if (ar < M) {
            const float* ap = &A[(long)ar * K + k0 + a_k];
            av0 = *(const float4*)ap;
            av1 = *(const float4*)(ap + 4);
        }
        As[a_k + 0][a_m] = av0.x; As[a_k + 1][a_m] = av0.y;
        As[a_k + 2][a_m] = av0.z; As[a_k + 3][a_m] = av0.w;
        As[a_k + 4][a_m] = av1.x; As[a_k + 5][a_m] = av1.y;
        As[a_k + 6][a_m] = av1.z; As[a_k + 7][a_m] = av1.w;
        #pragma unroll
        for (int hh = 0; hh < 2; ++hh)
            *(float4*)&Ws[hh][w_k][w_n] =
                *(const float4*)&W[(long)(k0 + w_k) * N + colBase + hh * 64 + w_n];
        __syncthreads();
        #pragma unroll
        for (int kk = 0; kk < BK; ++kk) {
            float4 a0 = *(const float4*)&As[kk][ty << 3];
            float4 a1 = *(const float4*)&As[kk][(ty << 3) + 4];
            float ar8[8] = {a0.x, a0.y, a0.z, a0.w, a1.x, a1.y, a1.z, a1.w};
            #pragma unroll
            for (int hh = 0; hh < 2; ++hh) {
                float4 w = *(const float4*)&Ws[hh][kk][tx << 2];
                float wr[4] = {w.x, w.y, w.z, w.w};
                #pragma unroll
                for (int i = 0; i < 8; ++i)
                    #pragma unroll
                    for (int j = 0; j < 4; ++j)
                        acc[i][hh * 4 + j] += ar8[i] * wr[j];
            }
        }
        __syncthreads();
    }
    #pragma unroll
    for (int i = 0; i < 8; ++i) {
        int r = rowBase + (ty << 3) + i;
        if (r >= M) break;
        #pragma unroll
        for (int hh = 0; hh < 2; ++hh) {
            long cb = colBase + hh * 64 + (tx << 2);
            float4 o;
            o.x = acc[i][hh * 4 + 0] + bias[cb + 0];
            o.y = acc[i][hh * 4 + 1] + bias[cb + 1];
            o.z = acc[i][hh * 4 + 2] + bias[cb + 2];
            o.w = acc[i][hh * 4 + 3] + bias[cb + 3];
            *(float4*)&C[(long)r * N + cb] = o;
        }
    }
}

// ------------------------------------------------------------------
// SMALL fp32 GEMM: one WAVE (64 thr) per 32x32 output tile, 4x4 per
// thread, float4 LDS traffic. gridDim.z selects between two fully
// independent (A,W,bias,out) sets so paired GEMMs fuse into one
// launch (Wx+Wz, Df+Db). Fixes the round-5 disaster: 39-block
// launches at 2% VALUBusy -> 300-1200 one-wave blocks.
// SP applies correctly-rounded softplus (fp64-computed) in the
// epilogue; per-output FMA order is k-ascending = bit-identical to
// previous rounds. requires N%32==0, K%16==0.
// ------------------------------------------------------------------
#define SBK 16
template<bool SP, bool HASB2, bool HASRES>
__global__ __launch_bounds__(64) void gemm_s(const float* __restrict__ A0,
                                             const float* __restrict__ W0,
                                             const float* __restrict__ b10,
                                             const float* __restrict__ b20,
                                             const float* __restrict__ r0,
                                             float* __restrict__ C0,
                                             const float* __restrict__ A1,
                                             const float* __restrict__ W1,
                                             const float* __restrict__ b11,
                                             const float* __restrict__ b21,
                                             const float* __restrict__ r1,
                                             float* __restrict__ C1,
                                             int M, int N, int K) {
    const float* A  = blockIdx.z ? A1  : A0;
    const float* W  = blockIdx.z ? W1  : W0;
    const float* bp = blockIdx.z ? b11 : b10;
    const float* b2 = blockIdx.z ? b21 : b20;
    const float* rp = blockIdx.z ? r1  : r0;
    float*       C  = blockIdx.z ? C1  : C0;
    __shared__ float As[SBK][36];   // +4 pad keeps 16B alignment, breaks banks
    __shared__ float Wsh[SBK][36];
    int t = threadIdx.x;            // 0..63
    int tx = t & 7, ty = t >> 3;
    int rowBase = blockIdx.y * 32;
    long colBase = (long)blockIdx.x * 32;
    // A staging map: float4 idx i in [0,128): row=i>>2, kq=(i&3)<<2 ; thread does i=t, t+64
    int rA = t >> 2, kqA = (t & 3) << 2;
    // W staging map: float4 idx j in [0,128): k=j>>3, nq=(j&7)<<2 ; thread does j=t, t+64
    int kW = t >> 3, nqW = (t & 7) << 2;
    float acc[4][4] = {};
    for (int k0 = 0; k0 < K; k0 += SBK) {
        int r0i = rowBase + rA;
        int r1i = r0i + 16;
        float4 a0 = make_float4(0.f, 0.f, 0.f, 0.f), a1 = a0;
        if (r0i < M) a0 = *(const float4*)&A[(long)r0i * K + k0 + kqA];
        if (r1i < M) a1 = *(const float4*)&A[(long)r1i * K + k0 + kqA];
        float4 w0 = *(const float4*)&W[(long)(k0 + kW) * N + colBase + nqW];
        float4 w1 = *(const float4*)&W[(long)(k0 + kW + 8) * N + colBase + nqW];
        __syncthreads();
        As[kqA + 0][rA] = a0.x; As[kqA + 1][rA] = a0.y;
        As[kqA + 2][rA] = a0.z; As[kqA + 3][rA] = a0.w;
        As[kqA + 0][rA + 16] = a1.x; As[kqA + 1][rA + 16] = a1.y;
        As[kqA + 2][rA + 16] = a1.z; As[kqA + 3][rA + 16] = a1.w;
        *(float4*)&Wsh[kW][nqW]     = w0;
        *(float4*)&Wsh[kW + 8][nqW] = w1;
        __syncthreads();
        #pragma unroll
        for (int kk = 0; kk < SBK; ++kk) {
            float4 av = *(const float4*)&As[kk][ty << 2];
            float4 wv = *(const float4*)&Wsh[kk][tx << 2];
            float ar[4] = {av.x, av.y, av.z, av.w};
            float wr[4] = {wv.x, wv.y, wv.z, wv.w};
            #pragma unroll
            for (int i = 0; i < 4; ++i)
                #pragma unroll
                for (int j = 0; j < 4; ++j) acc[i][j] += ar[i] * wr[j];
        }
        __syncthreads();
    }
    #pragma unroll
    for (int i = 0; i < 4; ++i) {
        int r = rowBase + (ty << 2) + i;
        if (r >= M) break;
        long cb = colBase + (tx << 2);
        float vv[4];
        #pragma unroll
        for (int j = 0; j < 4; ++j) {
            float v = acc[i][j] + bp[cb + j];
            if (HASB2) v += b2[cb + j];
            if (SP) {  // correctly-rounded fp32 softplus via fp64
                double vd = (double)v;
                v = (float)(log1p(exp(-fabs(vd))) + fmax(vd, 0.0));
            }
            if (HASRES) v += rp[(long)r * N + cb + j];
            vv[j] = v;
        }
        float4 o; o.x = vv[0]; o.y = vv[1]; o.z = vv[2]; o.w = vv[3];
        *(float4*)&C[(long)r * N + cb] = o;
    }
}

// ------------------------------------------------------------------
// fused depthwise conv (fwd + bwd) + SiLU
// ------------------------------------------------------------------
__global__ __launch_bounds__(256) void dwconv_k(const float* __restrict__ xp,
                                                const float* __restrict__ wf,
                                                const float* __restrict__ bf,
                                                const float* __restrict__ wb,
                                                const float* __restrict__ bb,
                                                float* __restrict__ xf,
                                                float* __restrict__ xb) {
    int idx = blockIdx.x * 256 + threadIdx.x;
    if (idx >= ROWS * EDIM) return;
    int e = idx % EDIM;
    int bm = idx / EDIM;
    int m = bm % MSEQ, b = bm / MSEQ;
    const float* base = xp + (long)b * MSEQ * EDIM + e;
    float xm1 = (m > 0)        ? base[(m - 1) * EDIM] : 0.f;
    float x0  =                  base[m * EDIM];
    float xp1 = (m < MSEQ - 1) ? base[(m + 1) * EDIM] : 0.f;
    float f = wf[e * 3 + 0] * xm1 + wf[e * 3 + 1] * x0 + wf[e * 3 + 2] * xp1 + bf[e];
    float r = wb[e * 3 + 0] * xp1 + wb[e * 3 + 1] * x0 + wb[e * 3 + 2] * xm1 + bb[e];
    xf[idx] = silu_f(f);
    xb[idx] = silu_f(r);
}

// ------------------------------------------------------------------
// SSM recurrence — fp32 storage semantics, CR transcendentals
// (fp64-computed, rounded to fp32). Delta precomputed (CR softplus in
// the D-GEMM epilogue). Arithmetic is bit-identical to round 4; the
// only change is software prefetch of the next-step operands so the
// ~200-cycle load latency overlaps the fp64 log/exp chain.
// fp contract OFF so the S/h chain rounds exactly like numpy.
// ------------------------------------------------------------------
__global__ __launch_bounds__(64) void ssm_scan_k(const float* __restrict__ Bm,
                                                 const float* __restrict__ Cm,
                                                 const float* __restrict__ Dlt,
                                                 const float* __restrict__ xs,
                                                 const float* __restrict__ Apar,
                                                 float* __restrict__ y) {
#pragma clang fp contract(off)
    int tid = blockIdx.x * 64 + threadIdx.x;     // B*E*N total = 49152
    int n = tid & (NSTATE - 1);
    int e = (tid / NSTATE) % EDIM;
    int b = tid / (EDIM * NSTATE);
    float Ap = Apar[e * NSTATE + n];
    float cumlog = 0.f, cumsign = 1.f, S = 0.f;
    int bcIdx = b * MSEQ * ENDIM + e * NSTATE + n;   // advances by ENDIM per m
    int dxIdx = b * MSEQ * EDIM + e;                 // advances by EDIM per m
    bool leader = ((threadIdx.x & 15) == 0);
    float delta = Dlt[dxIdx], xv = xs[dxIdx], Bv = Bm[bcIdx], Cv = Cm[bcIdx];
    for (int m = 0; m < MSEQ; ++m) {
        int dxN = dxIdx + EDIM, bcN = bcIdx + ENDIM;
        float dN = 0.f, xN = 0.f, BN2 = 0.f, CN = 0.f;
        if (m + 1 < MSEQ) {                           // prefetch next step
            dN = Dlt[dxN]; xN = xs[dxN]; BN2 = Bm[bcN]; CN = Cm[bcN];
        }
        float A = delta * Ap;                         // exact fp32 product
        float sa = (A > 0.f) ? 1.f : ((A < 0.f) ? -1.f : 0.f);
        cumsign = cumsign * sa;
        float absA = fmaxf(fabsf(A), 1e-6f);
        float lg = (float)log((double)absA);          // CR fp32 log
        cumlog = cumlog + lg;                         // fp32 cumsum
        float ex = (float)exp((double)cumlog);        // CR fp32 exp
        float P = cumsign * ex;
        float tt = P + 1e-6f;                         // exact near-cancel
        float invP = 1.0f / tt;                       // IEEE fp32 div
        float Bfull = delta * Bv;
        float t1 = invP * Bfull;
        float t2 = t1 * xv;
        S = S + t2;
        float h = P * S;
        float contrib = h * Cv;
        // numpy pairwise-16 reduction order
        contrib += __shfl_xor(contrib, 8);
        contrib += __shfl_xor(contrib, 1);
        contrib += __shfl_xor(contrib, 2);
        contrib += __shfl_xor(contrib, 4);
        if (leader) y[dxIdx] = contrib;
        delta = dN; xv = xN; Bv = BN2; Cv = CN;
        dxIdx = dxN; bcIdx = bcN;
    }
}

// ------------------------------------------------------------------
// combine: yc = (yf + yb) * silu(z)
// ------------------------------------------------------------------
__global__ __launch_bounds__(256) void combine_k(const float* __restrict__ yf,
                                                 const float* __restrict__ yb,
                                                 const float* __restrict__ z,
                                                 float* __restrict__ yc) {
    int idx = blockIdx.x * 256 + threadIdx.x;
    if (idx >= ROWS * EDIM) return;
    yc[idx] = (yf[idx] + yb[idx]) * silu_f(z[idx]);
}

extern "C" void kernel_launch(void* const* d_in, const int* in_sizes, int n_in,
                              void* d_out, int out_size, void* d_ws, size_t ws_size,
                              hipStream_t stream) {
    const float* img     = (const float*)d_in[0];
    const float* patch_w = (const float*)d_in[1];
    const float* patch_b = (const float*)d_in[2];
    const float* cls     = (const float*)d_in[3];
    const float* pos     = (const float*)d_in[4];
    const float* ln_g    = (const float*)d_in[5];
    const float* ln_b    = (const float*)d_in[6];
    const float* Wx  = (const float*)d_in[7];  const float* bx  = (const float*)d_in[8];
    const float* Wz  = (const float*)d_in[9];  const float* bz  = (const float*)d_in[10];
    const float* cwf = (const float*)d_in[11]; const float* cbf = (const float*)d_in[12];
    const float* cwb = (const float*)d_in[13]; const float* cbb = (const float*)d_in[14];
    const float* WBf = (const float*)d_in[15]; const float* bBf = (const float*)d_in[16];
    const float* WCf = (const float*)d_in[17]; const float* bCf = (const float*)d_in[18];
    const float* WDf = (const float*)d_in[19]; const float* bDf = (const float*)d_in[20];
    const float* Af  = (const float*)d_in[21]; const float* dbf = (const float*)d_in[22];
    const float* WBb = (const float*)d_in[23]; const float* bBb = (const float*)d_in[24];
    const float* WCb = (const float*)d_in[25]; const float* bCb = (const float*)d_in[26];
    const float* WDb = (const float*)d_in[27]; const float* bDb = (const float*)d_in[28];
    const float* Ab  = (const float*)d_in[29]; const float* dbb = (const float*)d_in[30];
    const float* Wout= (const float*)d_in[31]; const float* bout= (const float*)d_in[32];
    const float* ng  = (const float*)d_in[33]; const float* nb  = (const float*)d_in[34];

    float* ws = (float*)d_ws;
    float* xA   = ws;
    float* xB   = xA  + (size_t)ROWS * DDIM;
    float* xn   = xB  + (size_t)ROWS * DDIM;
    float* xp   = xn  + (size_t)ROWS * DDIM;
    float* zb   = xp  + (size_t)ROWS * EDIM;
    float* xfb  = zb  + (size_t)ROWS * EDIM;
    float* xbb  = xfb + (size_t)ROWS * EDIM;
    float* yfb  = xbb + (size_t)ROWS * EDIM;
    float* ybb  = yfb + (size_t)ROWS * EDIM;
    float* ycb  = ybb + (size_t)ROWS * EDIM;
    float* dlt  = ycb + (size_t)ROWS * EDIM;
    float* dlt2 = dlt + (size_t)ROWS * EDIM;
    float* Bmb  = dlt2 + (size_t)ROWS * EDIM;        // ROWS*ENDIM
    float* Cmb  = Bmb + (size_t)ROWS * ENDIM;
    // patchify scratch aliases the (not-yet-needed) Bm buffer
    float* patches = Bmb;                             // PROWS*PATCH_K
    float* xemb    = Bmb + (size_t)PROWS * PATCH_K;   // PROWS*DDIM

    // --- patch embedding ---
    patchify_k<<<(PROWS * PATCH_K + 255) / 256, 256, 0, stream>>>(img, patches);
    {   // 1568x192x768 GEMM: grid (6,49,1) one-wave tiles
        dim3 g(DDIM / 32, (PROWS + 31) / 32, 1);
        gemm_s<false, false, false><<<g, 64, 0, stream>>>(
            patches, patch_w, patch_b, nullptr, nullptr, xemb,
            patches, patch_w, patch_b, nullptr, nullptr, xemb,
            PROWS, DDIM, PATCH_K);
    }
    assemble_k<<<(ROWS * DDIM + 255) / 256, 256, 0, stream>>>(xemb, cls, pos, xA);

    float* cur = xA; float* nxt = xB;
    for (int i = 0; i < LLAYERS; ++i) {
        layernorm_k<<<(ROWS + 3) / 4, 256, 0, stream>>>(cur, ln_g + i * DDIM, ln_b + i * DDIM, xn, ROWS);
        {   // Wx + Wz fused (shared A=xn): grid (12,50,2)
            dim3 g(EDIM / 32, (ROWS + 31) / 32, 2);
            gemm_s<false, false, false><<<g, 64, 0, stream>>>(
                xn, Wx + (size_t)i * DDIM * EDIM, bx + i * EDIM, nullptr, nullptr, xp,
                xn, Wz + (size_t)i * DDIM * EDIM, bz + i * EDIM, nullptr, nullptr, zb,
                ROWS, EDIM, DDIM);
        }
        dwconv_k<<<(ROWS * EDIM + 255) / 256, 256, 0, stream>>>(xp, cwf + i * EDIM * 3, cbf + i * EDIM,
                                                                cwb + i * EDIM * 3, cbb + i * EDIM, xfb, xbb);
        {   // Bf + Cf fused (shared A=xfb): grid (48,13,2)
            dim3 g(ENDIM / 128, (ROWS + BM - 1) / BM, 2);
            gemm_big<<<g, 256, 0, stream>>>(
                xfb, WBf + (size_t)i * EDIM * ENDIM, bBf + i * ENDIM, Bmb,
                     WCf + (size_t)i * EDIM * ENDIM, bCf + i * ENDIM, Cmb,
                ROWS, ENDIM, EDIM);
        }
        {   // Df + Db fused (CR softplus epilogue): grid (12,50,2)
            dim3 g(EDIM / 32, (ROWS + 31) / 32, 2);
            gemm_s<true, true, false><<<g, 64, 0, stream>>>(
                xfb, WDf + (size_t)i * EDIM * EDIM, bDf + i * EDIM, dbf + i * EDIM, nullptr, dlt,
                xbb, WDb + (size_t)i * EDIM * EDIM, bDb + i * EDIM, dbb + i * EDIM, nullptr, dlt2,
                ROWS, EDIM, EDIM);
        }
        ssm_scan_k<<<(BATCH * EDIM * NSTATE) / 64, 64, 0, stream>>>(Bmb, Cmb, dlt, xfb, Af + i * EDIM * NSTATE, yfb);
        {   // Bb + Cb fused (shared A=xbb)
            dim3 g(ENDIM / 128, (ROWS + BM - 1) / BM, 2);
            gemm_big<<<g, 256, 0, stream>>>(
                xbb, WBb + (size_t)i * EDIM * ENDIM, bBb + i * ENDIM, Bmb,
                     WCb + (size_t)i * EDIM * ENDIM, bCb + i * ENDIM, Cmb,
                ROWS, ENDIM, EDIM);
        }
        ssm_scan_k<<<(BATCH * EDIM * NSTATE) / 64, 64, 0, stream>>>(Bmb, Cmb, dlt2, xbb, Ab + i * EDIM * NSTATE, ybb);

        combine_k<<<(ROWS * EDIM + 255) / 256, 256, 0, stream>>>(yfb, ybb, zb, ycb);
        {   // Wout with residual: grid (6,50,1)
            dim3 g(DDIM / 32, (ROWS + 31) / 32, 1);
            gemm_s<false, false, true><<<g, 64, 0, stream>>>(
                ycb, Wout + (size_t)i * EDIM * DDIM, bout + i * DDIM, nullptr, cur, nxt,
                ycb, Wout + (size_t)i * EDIM * DDIM, bout + i * DDIM, nullptr, cur, nxt,
                ROWS, DDIM, EDIM);
        }
        float* t = cur; cur = nxt; nxt = t;
    }
    layernorm_k<<<(ROWS + 3) / 4, 256, 0, stream>>>(cur, ng, nb, (float*)d_out, ROWS);
}

// Round 7
// 1210.036 us; speedup vs baseline: 2.2920x; 1.1774x over previous
//
#include <hip/hip_runtime.h>
#include <hip/hip_bf16.h>
#include <math.h>

// ---- problem constants ----
#define BATCH   8
#define C_IN    3
#define IMG_SZ  224
#define P_SZ    16
#define NPATCH  196                 // (224/16)^2
#define MSEQ    197                 // NPATCH + cls
#define DDIM    192
#define EDIM    384
#define NSTATE  16
#define ENDIM   (EDIM*NSTATE)       // 6144
#define LLAYERS 2
#define ROWS    (BATCH*MSEQ)        // 1576
#define PROWS   (BATCH*NPATCH)      // 1568
#define PATCH_K (C_IN*P_SZ*P_SZ)    // 768

// precise silu (enters the scan only linearly)
__device__ __forceinline__ float silu_f(float x) { return x / (1.f + expf(-x)); }

// ------------------------------------------------------------------
// patchify: img (B,3,224,224) -> patches (PROWS, 768)
// ------------------------------------------------------------------
__global__ __launch_bounds__(256) void patchify_k(const float* __restrict__ img,
                                                  float* __restrict__ out) {
    int idx = blockIdx.x * 256 + threadIdx.x;
    if (idx >= PROWS * PATCH_K) return;
    int r = idx / PATCH_K, col = idx - r * PATCH_K;
    int b = r / NPATCH, p = r - b * NPATCH;
    int ph = p / 14, pw = p - ph * 14;
    int c = col >> 8, rem = col & 255, py = rem >> 4, px = rem & 15;
    out[idx] = img[((b * C_IN + c) * IMG_SZ + ph * P_SZ + py) * IMG_SZ + pw * P_SZ + px];
}

// ------------------------------------------------------------------
// assemble x = concat(cls, xemb) + pos   -> (B, MSEQ, DDIM)
// ------------------------------------------------------------------
__global__ __launch_bounds__(256) void assemble_k(const float* __restrict__ xemb,
                                                  const float* __restrict__ cls,
                                                  const float* __restrict__ pos,
                                                  float* __restrict__ x) {
    int idx = blockIdx.x * 256 + threadIdx.x;
    if (idx >= ROWS * DDIM) return;
    int d = idx % DDIM;
    int bm = idx / DDIM;
    int m = bm % MSEQ, b = bm / MSEQ;
    float v;
    if (m == 0) v = cls[d];
    else        v = xemb[((b * NPATCH) + (m - 1)) * DDIM + d];
    x[idx] = v + pos[m * DDIM + d];
}

// ------------------------------------------------------------------
// layernorm over last dim (DDIM=192), one wave per row
// ------------------------------------------------------------------
__global__ __launch_bounds__(256) void layernorm_k(const float* __restrict__ x,
                                                   const float* __restrict__ g,
                                                   const float* __restrict__ b,
                                                   float* __restrict__ o, int nrows) {
    int wave = threadIdx.x >> 6;
    int lane = threadIdx.x & 63;
    int row = blockIdx.x * 4 + wave;
    if (row >= nrows) return;
    const float* xr = x + (long)row * DDIM;
    float v0 = xr[lane], v1 = xr[lane + 64], v2 = xr[lane + 128];
    float s = v0 + v1 + v2;
    #pragma unroll
    for (int off = 1; off < 64; off <<= 1) s += __shfl_xor(s, off);
    float mu = s * (1.f / 192.f);
    float d0 = v0 - mu, d1 = v1 - mu, d2 = v2 - mu;
    float q = d0 * d0 + d1 * d1 + d2 * d2;
    #pragma unroll
    for (int off = 1; off < 64; off <<= 1) q += __shfl_xor(q, off);
    float inv = rsqrtf(q * (1.f / 192.f) + 1e-5f);
    float* orow = o + (long)row * DDIM;
    orow[lane]       = d0 * inv * g[lane]       + b[lane];
    orow[lane + 64]  = d1 * inv * g[lane + 64]  + b[lane + 64];
    orow[lane + 128] = d2 * inv * g[lane + 128] + b[lane + 128];
}

// ------------------------------------------------------------------
// BIG fp32 GEMM for the B/C projections (N=6144), tile 128x128,
// 8x8 per thread, 256 threads, DOUBLE-BUFFERED LDS (1 barrier/K-step;
// next tile's global loads issue before compute -> latency hidden).
// gridDim.z=2 selects {W0->C0, W1->C1} with the SAME A.
// ------------------------------------------------------------------
#define BM 128
#define BK 16
__global__ __launch_bounds__(256) void gemm_big(const float* __restrict__ A,
                                                const float* __restrict__ W0,
                                                const float* __restrict__ b0,
                                                float* __restrict__ C0,
                                                const float* __restrict__ W1,
                                                const float* __restrict__ b1,
                                                float* __restrict__ C1,
                                                int M, int N, int K) {
    const float* W    = blockIdx.z ? W1 : W0;
    const float* bias = blockIdx.z ? b1 : b0;
    float*       C    = blockIdx.z ? C1 : C0;
    __shared__ float As[2][BK][BM + 4];
    __shared__ float Ws[2][2][BK][64];
    int t = threadIdx.x;
    int tx = t & 15, ty = t >> 4;
    long colBase = (long)blockIdx.x * 128;
    int rowBase = blockIdx.y * BM;
    float acc[8][8] = {};
    int a_m = t >> 1, a_k = (t & 1) << 3;      // A: 2 float4 per thread
    int w_k = t >> 4, w_n = (t & 15) << 2;     // W: 1 float4 per panel per thread
    int ar = rowBase + a_m;
    const float* aptr = &A[(long)ar * K + a_k];

    auto stage = [&](int buf, float4 av0, float4 av1, float4 w0, float4 w1) {
        As[buf][a_k + 0][a_m] = av0.x; As[buf][a_k + 1][a_m] = av0.y;
        As[buf][a_k + 2][a_m] = av0.z; As[buf][a_k + 3][a_m] = av0.w;
        As[buf][a_k + 4][a_m] = av1.x; As[buf][a_k + 5][a_m] = av1.y;
        As[buf][a_k + 6][a_m] = av1.z; As[buf][a_k + 7][a_m] = av1.w;
        *(float4*)&Ws[buf][0][w_k][w_n] = w0;
        *(float4*)&Ws[buf][1][w_k][w_n] = w1;
    };
    auto compute = [&](int buf) {
        #pragma unroll
        for (int kk = 0; kk < BK; ++kk) {
            float4 a0 = *(const float4*)&As[buf][kk][ty << 3];
            float4 a1 = *(const float4*)&As[buf][kk][(ty << 3) + 4];
            float ar8[8] = {a0.x, a0.y, a0.z, a0.w, a1.x, a1.y, a1.z, a1.w};
            #pragma unroll
            for (int hh = 0; hh < 2; ++hh) {
                float4 w = *(const float4*)&Ws[buf][hh][kk][tx << 2];
                float wr[4] = {w.x, w.y, w.z, w.w};
                #pragma unroll
                for (int i = 0; i < 8; ++i)
                    #pragma unroll
                    for (int j = 0; j < 4; ++j)
                        acc[i][hh * 4 + j] += ar8[i] * wr[j];
            }
        }
    };

    // prologue: tile 0
    {
        float4 av0 = make_float4(0.f,0.f,0.f,0.f), av1 = av0;
        if (ar < M) { av0 = *(const float4*)aptr; av1 = *(const float4*)(aptr + 4); }
        float4 w0 = *(const float4*)&W[(long)w_k * N + colBase + w_n];
        float4 w1 = *(const float4*)&W[(long)w_k * N + colBase + 64 + w_n];
        stage(0, av0, av1, w0, w1);
    }
    __syncthreads();
    int cur = 0;
    int nt = K / BK;
    for (int kt = 1; kt < nt; ++kt) {
        int k0 = kt * BK;
        float4 av0 = make_float4(0.f,0.f,0.f,0.f), av1 = av0;
        if (ar < M) { av0 = *(const float4*)(aptr + k0); av1 = *(const float4*)(aptr + k0 + 4); }
        float4 w0 = *(const float4*)&W[(long)(k0 + w_k) * N + colBase + w_n];
        float4 w1 = *(const float4*)&W[(long)(k0 + w_k) * N + colBase + 64 + w_n];
        compute(cur);                 // overlaps the loads above
        stage(cur ^ 1, av0, av1, w0, w1);
        __syncthreads();
        cur ^= 1;
    }
    compute(cur);

    #pragma unroll
    for (int i = 0; i < 8; ++i) {
        int r = rowBase + (ty << 3) + i;
        if (r >= M) break;
        #pragma unroll
        for (int hh = 0; hh < 2; ++hh) {
            long cb = colBase + hh * 64 + (tx << 2);
            float4 o;
            o.x = acc[i][hh * 4 + 0] + bias[cb + 0];
            o.y = acc[i][hh * 4 + 1] + bias[cb + 1];
            o.z = acc[i][hh * 4 + 2] + bias[cb + 2];
            o.w = acc[i][hh * 4 + 3] + bias[cb + 3];
            *(float4*)&C[(long)r * N + cb] = o;
        }
    }
}

// ------------------------------------------------------------------
// SMALL fp32 GEMM: one WAVE per 32x32 tile, 4x4/thread, double-
// buffered LDS (1 barrier/K-step). gridDim.z selects two independent
// (A,W,bias,out) sets (Wx+Wz, Df+Db). SP = correctly-rounded softplus
// epilogue. Per-output FMA order k-ascending = bit-identical.
// ------------------------------------------------------------------
#define SBK 16
template<bool SP, bool HASB2, bool HASRES>
__global__ __launch_bounds__(64) void gemm_s(const float* __restrict__ A0,
                                             const float* __restrict__ W0,
                                             const float* __restrict__ b10,
                                             const float* __restrict__ b20,
                                             const float* __restrict__ r0,
                                             float* __restrict__ C0,
                                             const float* __restrict__ A1,
                                             const float* __restrict__ W1,
                                             const float* __restrict__ b11,
                                             const float* __restrict__ b21,
                                             const float* __restrict__ r1,
                                             float* __restrict__ C1,
                                             int M, int N, int K) {
    const float* A  = blockIdx.z ? A1  : A0;
    const float* W  = blockIdx.z ? W1  : W0;
    const float* bp = blockIdx.z ? b11 : b10;
    const float* b2 = blockIdx.z ? b21 : b20;
    const float* rp = blockIdx.z ? r1  : r0;
    float*       C  = blockIdx.z ? C1  : C0;
    __shared__ float As[2][SBK][36];
    __shared__ float Wsh[2][SBK][36];
    int t = threadIdx.x;            // 0..63
    int tx = t & 7, ty = t >> 3;
    int rowBase = blockIdx.y * 32;
    long colBase = (long)blockIdx.x * 32;
    int rA = t >> 2, kqA = (t & 3) << 2;
    int kW = t >> 3, nqW = (t & 7) << 2;
    float acc[4][4] = {};
    int r0i = rowBase + rA, r1i = r0i + 16;

    auto loadA = [&](int k0, float4& a0, float4& a1) {
        a0 = make_float4(0.f,0.f,0.f,0.f); a1 = a0;
        if (r0i < M) a0 = *(const float4*)&A[(long)r0i * K + k0 + kqA];
        if (r1i < M) a1 = *(const float4*)&A[(long)r1i * K + k0 + kqA];
    };
    auto stage = [&](int buf, float4 a0, float4 a1, float4 w0, float4 w1) {
        As[buf][kqA + 0][rA] = a0.x; As[buf][kqA + 1][rA] = a0.y;
        As[buf][kqA + 2][rA] = a0.z; As[buf][kqA + 3][rA] = a0.w;
        As[buf][kqA + 0][rA + 16] = a1.x; As[buf][kqA + 1][rA + 16] = a1.y;
        As[buf][kqA + 2][rA + 16] = a1.z; As[buf][kqA + 3][rA + 16] = a1.w;
        *(float4*)&Wsh[buf][kW][nqW]     = w0;
        *(float4*)&Wsh[buf][kW + 8][nqW] = w1;
    };
    auto compute = [&](int buf) {
        #pragma unroll
        for (int kk = 0; kk < SBK; ++kk) {
            float4 av = *(const float4*)&As[buf][kk][ty << 2];
            float4 wv = *(const float4*)&Wsh[buf][kk][tx << 2];
            float ar[4] = {av.x, av.y, av.z, av.w};
            float wr[4] = {wv.x, wv.y, wv.z, wv.w};
            #pragma unroll
            for (int i = 0; i < 4; ++i)
                #pragma unroll
                for (int j = 0; j < 4; ++j) acc[i][j] += ar[i] * wr[j];
        }
    };

    {
        float4 a0, a1;
        loadA(0, a0, a1);
        float4 w0 = *(const float4*)&W[(long)kW * N + colBase + nqW];
        float4 w1 = *(const float4*)&W[(long)(kW + 8) * N + colBase + nqW];
        stage(0, a0, a1, w0, w1);
    }
    __syncthreads();
    int cur = 0;
    int nt = K / SBK;
    for (int kt = 1; kt < nt; ++kt) {
        int k0 = kt * SBK;
        float4 a0, a1;
        loadA(k0, a0, a1);
        float4 w0 = *(const float4*)&W[(long)(k0 + kW) * N + colBase + nqW];
        float4 w1 = *(const float4*)&W[(long)(k0 + kW + 8) * N + colBase + nqW];
        compute(cur);
        stage(cur ^ 1, a0, a1, w0, w1);
        __syncthreads();
        cur ^= 1;
    }
    compute(cur);

    #pragma unroll
    for (int i = 0; i < 4; ++i) {
        int r = rowBase + (ty << 2) + i;
        if (r >= M) break;
        long cb = colBase + (tx << 2);
        float vv[4];
        #pragma unroll
        for (int j = 0; j < 4; ++j) {
            float v = acc[i][j] + bp[cb + j];
            if (HASB2) v += b2[cb + j];
            if (SP) {  // correctly-rounded fp32 softplus via fp64
                double vd = (double)v;
                v = (float)(log1p(exp(-fabs(vd))) + fmax(vd, 0.0));
            }
            if (HASRES) v += rp[(long)r * N + cb + j];
            vv[j] = v;
        }
        float4 o; o.x = vv[0]; o.y = vv[1]; o.z = vv[2]; o.w = vv[3];
        *(float4*)&C[(long)r * N + cb] = o;
    }
}

// ------------------------------------------------------------------
// fused depthwise conv (fwd + bwd) + SiLU
// ------------------------------------------------------------------
__global__ __launch_bounds__(256) void dwconv_k(const float* __restrict__ xp,
                                                const float* __restrict__ wf,
                                                const float* __restrict__ bf,
                                                const float* __restrict__ wb,
                                                const float* __restrict__ bb,
                                                float* __restrict__ xf,
                                                float* __restrict__ xb) {
    int idx = blockIdx.x * 256 + threadIdx.x;
    if (idx >= ROWS * EDIM) return;
    int e = idx % EDIM;
    int bm = idx / EDIM;
    int m = bm % MSEQ, b = bm / MSEQ;
    const float* base = xp + (long)b * MSEQ * EDIM + e;
    float xm1 = (m > 0)        ? base[(m - 1) * EDIM] : 0.f;
    float x0  =                  base[m * EDIM];
    float xp1 = (m < MSEQ - 1) ? base[(m + 1) * EDIM] : 0.f;
    float f = wf[e * 3 + 0] * xm1 + wf[e * 3 + 1] * x0 + wf[e * 3 + 2] * xp1 + bf[e];
    float r = wb[e * 3 + 0] * xp1 + wb[e * 3 + 1] * x0 + wb[e * 3 + 2] * xm1 + bb[e];
    xf[idx] = silu_f(f);
    xb[idx] = silu_f(r);
}

// ------------------------------------------------------------------
// SSM recurrence, PHASE-PARALLEL, bit-exact vs the sequential version:
// the per-(m,n) transcendentals (CR fp64 log/exp) are embarrassingly
// parallel; only the fp32 cumsum chains (cumlog, cumsign, S) are
// serial — and those are cheap adds done in the SAME ascending-m
// order, so every fp32 op and its rounding is identical to rounds 4-6.
// One block per (b,e): 197x16 elements in LDS.
//   p1 (par): lg=CRlog(max(|delta*Ap|,1e-6)), sa=sign       -> LDS
//   p2 (16 thr): cumlog += lg, cumsign *= sa (serial m)     -> LDS
//   p3 (par): P=cs*CRexp(cl); term=(1/(P+1e-6))*(delta*B)*x -> LDS
//   p4 (16 thr): S += term; h = P*S (serial m)              -> LDS
//   p5 (par over m): y = pairwise-16 tree of h*C (numpy order)
// ------------------------------------------------------------------
__global__ __launch_bounds__(256) void ssm_scan_k(const float* __restrict__ Bm,
                                                  const float* __restrict__ Cm,
                                                  const float* __restrict__ Dlt,
                                                  const float* __restrict__ xs,
                                                  const float* __restrict__ Apar,
                                                  float* __restrict__ y) {
#pragma clang fp contract(off)
    __shared__ float lgP[MSEQ][17];        // lg -> cumlog -> P
    __shared__ float trm[MSEQ][17];        // term -> h
    __shared__ signed char sgn[MSEQ][17];  // sa -> cumsign
    int be = blockIdx.x;
    int b = be / EDIM, e = be - b * EDIM;
    int t = threadIdx.x;
    int n0 = t & 15;                       // fixed per thread (256 % 16 == 0)
    float Ap = Apar[e * NSTATE + n0];
    const long dxBase = (long)b * MSEQ * EDIM + e;
    const long bcBase = (long)b * MSEQ * ENDIM + e * NSTATE;

    // phase 1
    for (int idx = t; idx < MSEQ * NSTATE; idx += 256) {
        int m = idx >> 4;
        float delta = Dlt[dxBase + (long)m * EDIM];
        float A = delta * Ap;                              // exact fp32 product
        float sa = (A > 0.f) ? 1.f : ((A < 0.f) ? -1.f : 0.f);
        float absA = fmaxf(fabsf(A), 1e-6f);
        lgP[m][n0] = (float)log((double)absA);             // CR fp32 log
        sgn[m][n0] = (signed char)sa;
    }
    __syncthreads();
    // phase 2: serial per n — identical add order to the sequential scan
    if (t < NSTATE) {
        float cl = 0.f, cs = 1.f;
        for (int m = 0; m < MSEQ; ++m) {
            float sa = (float)sgn[m][t];
            cs = cs * sa;
            cl = cl + lgP[m][t];
            lgP[m][t] = cl;
            sgn[m][t] = (signed char)cs;
        }
    }
    __syncthreads();
    // phase 3
    for (int idx = t; idx < MSEQ * NSTATE; idx += 256) {
        int m = idx >> 4;
        float cl = lgP[m][n0];
        float cs = (float)sgn[m][n0];
        float ex = (float)exp((double)cl);                 // CR fp32 exp
        float P = cs * ex;
        float tt = P + 1e-6f;                              // exact near-cancel
        float invP = 1.0f / tt;                            // IEEE fp32 div
        float delta = Dlt[dxBase + (long)m * EDIM];
        float xv = xs[dxBase + (long)m * EDIM];
        float Bv = Bm[bcBase + (long)m * ENDIM + n0];
        float Bfull = delta * Bv;
        float t1 = invP * Bfull;
        float t2 = t1 * xv;
        trm[m][n0] = t2;
        lgP[m][n0] = P;
    }
    __syncthreads();
    // phase 4: serial per n — identical add order
    if (t < NSTATE) {
        float S = 0.f;
        for (int m = 0; m < MSEQ; ++m) {
            S = S + trm[m][t];
            float h = lgP[m][t] * S;
            trm[m][t] = h;
        }
    }
    __syncthreads();
    // phase 5: numpy pairwise-16 tree (xor8, xor1, xor2, xor4; lane-0 order)
    for (int m = t; m < MSEQ; m += 256) {
        const float* cp = &Cm[bcBase + (long)m * ENDIM];
        float a[16];
        #pragma unroll
        for (int n = 0; n < 16; ++n) a[n] = trm[m][n] * cp[n];
        float b0 = a[0] + a[8],  b1 = a[1] + a[9];
        float b2v = a[2] + a[10], b3 = a[3] + a[11];
        float b4 = a[4] + a[12], b5 = a[5] + a[13];
        float b6 = a[6] + a[14], b7 = a[7] + a[15];
        float c0 = b0 + b1, c2 = b2v + b3, c4 = b4 + b5, c6 = b6 + b7;
        float d0 = c0 + c2, d4 = c4 + c6;
        y[dxBase + (long)m * EDIM] = d0 + d4;
    }
}

// ------------------------------------------------------------------
// combine: yc = (yf + yb) * silu(z)
// ------------------------------------------------------------------
__global__ __launch_bounds__(256) void combine_k(const float* __restrict__ yf,
                                                 const float* __restrict__ yb,
                                                 const float* __restrict__ z,
                                                 float* __restrict__ yc) {
    int idx = blockIdx.x * 256 + threadIdx.x;
    if (idx >= ROWS * EDIM) return;
    yc[idx] = (yf[idx] + yb[idx]) * silu_f(z[idx]);
}

extern "C" void kernel_launch(void* const* d_in, const int* in_sizes, int n_in,
                              void* d_out, int out_size, void* d_ws, size_t ws_size,
                              hipStream_t stream) {
    const float* img     = (const float*)d_in[0];
    const float* patch_w = (const float*)d_in[1];
    const float* patch_b = (const float*)d_in[2];
    const float* cls     = (const float*)d_in[3];
    const float* pos     = (const float*)d_in[4];
    const float* ln_g    = (const float*)d_in[5];
    const float* ln_b    = (const float*)d_in[6];
    const float* Wx  = (const float*)d_in[7];  const float* bx  = (const float*)d_in[8];
    const float* Wz  = (const float*)d_in[9];  const float* bz  = (const float*)d_in[10];
    const float* cwf = (const float*)d_in[11]; const float* cbf = (const float*)d_in[12];
    const float* cwb = (const float*)d_in[13]; const float* cbb = (const float*)d_in[14];
    const float* WBf = (const float*)d_in[15]; const float* bBf = (const float*)d_in[16];
    const float* WCf = (const float*)d_in[17]; const float* bCf = (const float*)d_in[18];
    const float* WDf = (const float*)d_in[19]; const float* bDf = (const float*)d_in[20];
    const float* Af  = (const float*)d_in[21]; const float* dbf = (const float*)d_in[22];
    const float* WBb = (const float*)d_in[23]; const float* bBb = (const float*)d_in[24];
    const float* WCb = (const float*)d_in[25]; const float* bCb = (const float*)d_in[26];
    const float* WDb = (const float*)d_in[27]; const float* bDb = (const float*)d_in[28];
    const float* Ab  = (const float*)d_in[29]; const float* dbb = (const float*)d_in[30];
    const float* Wout= (const float*)d_in[31]; const float* bout= (const float*)d_in[32];
    const float* ng  = (const float*)d_in[33]; const float* nb  = (const float*)d_in[34];

    float* ws = (float*)d_ws;
    float* xA   = ws;
    float* xB   = xA  + (size_t)ROWS * DDIM;
    float* xn   = xB  + (size_t)ROWS * DDIM;
    float* xp   = xn  + (size_t)ROWS * DDIM;
    float* zb   = xp  + (size_t)ROWS * EDIM;
    float* xfb  = zb  + (size_t)ROWS * EDIM;
    float* xbb  = xfb + (size_t)ROWS * EDIM;
    float* yfb  = xbb + (size_t)ROWS * EDIM;
    float* ybb  = yfb + (size_t)ROWS * EDIM;
    float* ycb  = ybb + (size_t)ROWS * EDIM;
    float* dlt  = ycb + (size_t)ROWS * EDIM;
    float* dlt2 = dlt + (size_t)ROWS * EDIM;
    float* Bmb  = dlt2 + (size_t)ROWS * EDIM;        // ROWS*ENDIM
    float* Cmb  = Bmb + (size_t)ROWS * ENDIM;
    // patchify scratch aliases the (not-yet-needed) Bm buffer
    float* patches = Bmb;                             // PROWS*PATCH_K
    float* xemb    = Bmb + (size_t)PROWS * PATCH_K;   // PROWS*DDIM

    // --- patch embedding ---
    patchify_k<<<(PROWS * PATCH_K + 255) / 256, 256, 0, stream>>>(img, patches);
    {   // 1568x192x768 GEMM
        dim3 g(DDIM / 32, (PROWS + 31) / 32, 1);
        gemm_s<false, false, false><<<g, 64, 0, stream>>>(
            patches, patch_w, patch_b, nullptr, nullptr, xemb,
            patches, patch_w, patch_b, nullptr, nullptr, xemb,
            PROWS, DDIM, PATCH_K);
    }
    assemble_k<<<(ROWS * DDIM + 255) / 256, 256, 0, stream>>>(xemb, cls, pos, xA);

    float* cur = xA; float* nxt = xB;
    for (int i = 0; i < LLAYERS; ++i) {
        layernorm_k<<<(ROWS + 3) / 4, 256, 0, stream>>>(cur, ln_g + i * DDIM, ln_b + i * DDIM, xn, ROWS);
        {   // Wx + Wz fused (shared A=xn)
            dim3 g(EDIM / 32, (ROWS + 31) / 32, 2);
            gemm_s<false, false, false><<<g, 64, 0, stream>>>(
                xn, Wx + (size_t)i * DDIM * EDIM, bx + i * EDIM, nullptr, nullptr, xp,
                xn, Wz + (size_t)i * DDIM * EDIM, bz + i * EDIM, nullptr, nullptr, zb,
                ROWS, EDIM, DDIM);
        }
        dwconv_k<<<(ROWS * EDIM + 255) / 256, 256, 0, stream>>>(xp, cwf + i * EDIM * 3, cbf + i * EDIM,
                                                                cwb + i * EDIM * 3, cbb + i * EDIM, xfb, xbb);
        {   // Bf + Cf fused (shared A=xfb)
            dim3 g(ENDIM / 128, (ROWS + BM - 1) / BM, 2);
            gemm_big<<<g, 256, 0, stream>>>(
                xfb, WBf + (size_t)i * EDIM * ENDIM, bBf + i * ENDIM, Bmb,
                     WCf + (size_t)i * EDIM * ENDIM, bCf + i * ENDIM, Cmb,
                ROWS, ENDIM, EDIM);
        }
        {   // Df + Db fused (CR softplus epilogue)
            dim3 g(EDIM / 32, (ROWS + 31) / 32, 2);
            gemm_s<true, true, false><<<g, 64, 0, stream>>>(
                xfb, WDf + (size_t)i * EDIM * EDIM, bDf + i * EDIM, dbf + i * EDIM, nullptr, dlt,
                xbb, WDb + (size_t)i * EDIM * EDIM, bDb + i * EDIM, dbb + i * EDIM, nullptr, dlt2,
                ROWS, EDIM, EDIM);
        }
        ssm_scan_k<<<BATCH * EDIM, 256, 0, stream>>>(Bmb, Cmb, dlt, xfb, Af + i * EDIM * NSTATE, yfb);
        {   // Bb + Cb fused (shared A=xbb)
            dim3 g(ENDIM / 128, (ROWS + BM - 1) / BM, 2);
            gemm_big<<<g, 256, 0, stream>>>(
                xbb, WBb + (size_t)i * EDIM * ENDIM, bBb + i * ENDIM, Bmb,
                     WCb + (size_t)i * EDIM * ENDIM, bCb + i * ENDIM, Cmb,
                ROWS, ENDIM, EDIM);
        }
        ssm_scan_k<<<BATCH * EDIM, 256, 0, stream>>>(Bmb, Cmb, dlt2, xbb, Ab + i * EDIM * NSTATE, ybb);

        combine_k<<<(ROWS * EDIM + 255) / 256, 256, 0, stream>>>(yfb, ybb, zb, ycb);
        {   // Wout with residual
            dim3 g(DDIM / 32, (ROWS + 31) / 32, 1);
            gemm_s<false, false, true><<<g, 64, 0, stream>>>(
                ycb, Wout + (size_t)i * EDIM * DDIM, bout + i * DDIM, nullptr, cur, nxt,
                ycb, Wout + (size_t)i * EDIM * DDIM, bout + i * DDIM, nullptr, cur, nxt,
                ROWS, DDIM, EDIM);
        }
        float* t = cur; cur = nxt; nxt = t;
    }
    layernorm_k<<<(ROWS + 3) / 4, 256, 0, stream>>>(cur, ng, nb, (float*)d_out, ROWS);
}